// Round 1
// baseline (963.392 us; speedup 1.0000x reference)
//
#include <hip/hip_runtime.h>
#include <hip/hip_bf16.h>

#define N_NODES 30000
#define N_REL   8
#define N_EDGES 131072
#define FEAT    512
#define KTOT    4608   // 8*512 + 512
#define CAP     32

typedef __attribute__((ext_vector_type(8))) __bf16 v8bf;
typedef __attribute__((ext_vector_type(4))) __bf16 v4bf;
typedef __attribute__((ext_vector_type(4))) float  v4f;

// ---------- async global->LDS (16B per lane, wave-uniform LDS base) ----------
static __device__ __forceinline__ void load_lds16(const void* g, void* l) {
  __builtin_amdgcn_global_load_lds(
      (const __attribute__((address_space(1))) void*)g,
      (__attribute__((address_space(3))) void*)l, 16, 0, 0);
}

// ---------- fp32 -> bf16 convert of x ----------
__global__ void k_convert_x(const float* __restrict__ x, __bf16* __restrict__ xbf) {
  int i = blockIdx.x * 256 + threadIdx.x;           // each handles 4 elems
  float4 v = ((const float4*)x)[i];
  v4bf o;
  o[0] = (__bf16)v.x; o[1] = (__bf16)v.y; o[2] = (__bf16)v.z; o[3] = (__bf16)v.w;
  ((v4bf*)xbf)[i] = o;
}

// ---------- build W_t[n][k] = W_cat[k][n] (bf16), k = r*512+i or 4096+i ----------
__global__ void k_transpose_w(const float* __restrict__ w, const float* __restrict__ lw,
                              __bf16* __restrict__ Wt) {
  __shared__ float t[32][33];
  int k0 = blockIdx.x * 32;      // 144 blocks
  int n0 = blockIdx.y * 32;      // 16 blocks
  int tx = threadIdx.x & 31, ty = threadIdx.x >> 5;   // 32 x 8
  #pragma unroll
  for (int q = 0; q < 4; ++q) {
    int k = k0 + ty + q * 8, n = n0 + tx;
    float v = (k < 4096) ? w[(size_t)k * 512 + n] : lw[(size_t)(k - 4096) * 512 + n];
    t[ty + q * 8][tx] = v;
  }
  __syncthreads();
  #pragma unroll
  for (int q = 0; q < 4; ++q) {
    int n = n0 + ty + q * 8, k = k0 + tx;
    Wt[(size_t)n * KTOT + k] = (__bf16)t[tx][ty + q * 8];
  }
}

// ---------- bucket build: per-edge atomic slot insert ----------
__global__ void k_count(const int* __restrict__ src, const int* __restrict__ dst,
                        int* __restrict__ cnt, int* __restrict__ slots) {
  int e = blockIdx.x * 256 + threadIdx.x;           // 0 .. 8*131072-1
  int rel = e >> 17;
  int d = dst[e], s = src[e];
  int bucket = rel * N_NODES + d;
  int pos = atomicAdd(&cnt[bucket], 1);
  if (pos < CAP) slots[(size_t)bucket * CAP + pos] = s;
}

// ---------- aggregation: one wave per (rel,node); gather bf16 rows, fp32 acc ----------
__global__ void k_aggregate(const __bf16* __restrict__ xbf, const int* __restrict__ cnt,
                            const int* __restrict__ slots, __bf16* __restrict__ out,
                            int nBuckets) {
  int w = (blockIdx.x * blockDim.x + threadIdx.x) >> 6;
  int lane = threadIdx.x & 63;
  if (w >= nBuckets) return;
  int c = cnt[w];
  int cc = c < CAP ? c : CAP;
  const int* sl = slots + (size_t)w * CAP;
  float acc[8] = {0.f,0.f,0.f,0.f,0.f,0.f,0.f,0.f};
  for (int j = 0; j < cc; ++j) {
    int s = sl[j];
    v8bf v = *(const v8bf*)(xbf + (size_t)s * FEAT + lane * 8);
    #pragma unroll
    for (int t = 0; t < 8; ++t) acc[t] += (float)v[t];
  }
  float scale = 1.0f / (float)(c > 1 ? c : 1);
  v8bf o;
  #pragma unroll
  for (int t = 0; t < 8; ++t) o[t] = (__bf16)(acc[t] * scale);
  *(v8bf*)(out + (size_t)w * FEAT + lane * 8) = o;
}

// ---------- GEMM: C[M,512](+)= A[M,K] @ Wt[n][k]^T, 128x128 tile, mfma 16x16x32 bf16 ----------
template <bool ACCUM, bool FINAL>
__global__ __launch_bounds__(256, 2)
void k_gemm(const __bf16* __restrict__ A, size_t slabStride,
            const __bf16* __restrict__ Wt, int wtStride, int kTiles,
            const float* __restrict__ bias, float* __restrict__ C) {
  __shared__ __bf16 As[128 * 64];
  __shared__ __bf16 Bs[128 * 64];

  const int tid  = threadIdx.x;
  const int wave = tid >> 6;
  const int lane = tid & 63;
  const int lr = lane >> 3, lc = lane & 7;     // staging: row-in-chunk, 16B unit
  const int quad = lane >> 4, l15 = lane & 15; // mfma lane decomposition
  const int wRow = wave >> 1, wCol = wave & 1;

  const int mtile = blockIdx.x >> 2;
  const int ntile = blockIdx.x & 3;
  const int mBase = mtile * 128;
  const int nBase = ntile * 128;

  v4f acc[4][4];
  #pragma unroll
  for (int i = 0; i < 4; ++i)
    #pragma unroll
    for (int j = 0; j < 4; ++j) acc[i][j] = (v4f){0.f, 0.f, 0.f, 0.f};

  for (int kt = 0; kt < kTiles; ++kt) {
    const int kk = kt * 64;
    const __bf16* aT = A + (size_t)(kk >> 9) * slabStride + (kk & 511);
    #pragma unroll
    for (int t = 0; t < 4; ++t) {
      int chunk = wave * 4 + t;                 // 8 rows x 64 cols per chunk
      int row = mBase + chunk * 8 + lr;
      if (row > N_NODES - 1) row = N_NODES - 1; // clamp; masked at store
      load_lds16(aT + (size_t)row * FEAT + lc * 8, As + chunk * 512);
      int n = nBase + chunk * 8 + lr;
      load_lds16(Wt + (size_t)n * wtStride + kk + lc * 8, Bs + chunk * 512);
    }
    __syncthreads();
    #pragma unroll
    for (int ks = 0; ks < 2; ++ks) {
      v8bf af[4], bfr[4];
      #pragma unroll
      for (int mi = 0; mi < 4; ++mi) {
        int m = wRow * 64 + mi * 16 + l15;
        af[mi] = *(const v8bf*)(As + m * 64 + ks * 32 + quad * 8);
      }
      #pragma unroll
      for (int ni = 0; ni < 4; ++ni) {
        int n = wCol * 64 + ni * 16 + l15;
        bfr[ni] = *(const v8bf*)(Bs + n * 64 + ks * 32 + quad * 8);
      }
      #pragma unroll
      for (int mi = 0; mi < 4; ++mi)
        #pragma unroll
        for (int ni = 0; ni < 4; ++ni)
          acc[mi][ni] = __builtin_amdgcn_mfma_f32_16x16x32_bf16(af[mi], bfr[ni], acc[mi][ni], 0, 0, 0);
    }
    __syncthreads();
  }

  // epilogue: D row = quad*4+r, col = l15 within each 16x16 tile
  #pragma unroll
  for (int ni = 0; ni < 4; ++ni) {
    int col = nBase + wCol * 64 + ni * 16 + l15;
    float bv = FINAL ? bias[col] : 0.0f;
    #pragma unroll
    for (int mi = 0; mi < 4; ++mi) {
      int row0 = mBase + wRow * 64 + mi * 16 + quad * 4;
      #pragma unroll
      for (int r = 0; r < 4; ++r) {
        int row = row0 + r;
        if (row < N_NODES) {
          size_t idx = (size_t)row * FEAT + col;
          float v = acc[mi][ni][r];
          if (ACCUM) v += C[idx];
          if (FINAL) { v += bv; v = fmaxf(v, 0.0f); }
          C[idx] = v;
        }
      }
    }
  }
}

extern "C" void kernel_launch(void* const* d_in, const int* in_sizes, int n_in,
                              void* d_out, int out_size, void* d_ws, size_t ws_size,
                              hipStream_t stream) {
  const float* x    = (const float*)d_in[0];
  const float* w    = (const float*)d_in[1];
  const float* lw   = (const float*)d_in[2];
  const float* bias = (const float*)d_in[3];
  const int*   src  = (const int*)d_in[4];
  const int*   dst  = (const int*)d_in[5];
  float* out = (float*)d_out;

  char* ws = (char*)d_ws;
  const size_t SLAB  = (size_t)N_NODES * FEAT;            // elems per slab
  const size_t bigA  = 9 * SLAB * 2;                      // 276.5 MB
  const size_t wtB   = (size_t)FEAT * KTOT * 2;           // 4.7 MB
  const size_t cntB  = (size_t)N_REL * N_NODES * 4;       // 0.96 MB
  const size_t slotB = (size_t)N_REL * N_NODES * CAP * 4; // 30.7 MB
  const size_t needBig = bigA + wtB + cntB + slotB;

  const int nConvBlocks = (N_NODES * FEAT / 4) / 256;     // 15000
  const int nCountBlocks = (N_REL * N_EDGES) / 256;       // 4096

  if (ws_size >= needBig) {
    __bf16* Aslabs = (__bf16*)ws;
    __bf16* Wt     = (__bf16*)(ws + bigA);
    int*    cnt    = (int*)(ws + bigA + wtB);
    int*    slots  = (int*)(ws + bigA + wtB + cntB);
    __bf16* xbf    = Aslabs + 8 * SLAB;                   // slab 8 = x

    hipMemsetAsync(cnt, 0, cntB, stream);
    k_convert_x<<<nConvBlocks, 256, 0, stream>>>(x, xbf);
    k_transpose_w<<<dim3(KTOT / 32, FEAT / 32), 256, 0, stream>>>(w, lw, Wt);
    k_count<<<nCountBlocks, 256, 0, stream>>>(src, dst, cnt, slots);
    k_aggregate<<<(N_REL * N_NODES) / 4, 256, 0, stream>>>(xbf, cnt, slots, Aslabs,
                                                           N_REL * N_NODES);
    k_gemm<false, true><<<235 * 4, 256, 0, stream>>>(Aslabs, SLAB, Wt, KTOT,
                                                     KTOT / 64, bias, out);
  } else {
    // fallback: one agg slab reused, 9 accumulating GEMM passes (needs ~98 MB)
    __bf16* xbf   = (__bf16*)ws;
    __bf16* agg   = xbf + SLAB;
    __bf16* Wt    = (__bf16*)((char*)(agg + SLAB));
    int*    cnt   = (int*)((char*)Wt + wtB);
    int*    slots = cnt + N_REL * N_NODES;

    hipMemsetAsync(cnt, 0, cntB, stream);
    k_convert_x<<<nConvBlocks, 256, 0, stream>>>(x, xbf);
    k_transpose_w<<<dim3(KTOT / 32, FEAT / 32), 256, 0, stream>>>(w, lw, Wt);
    k_count<<<nCountBlocks, 256, 0, stream>>>(src, dst, cnt, slots);
    for (int r = 0; r < N_REL; ++r) {
      k_aggregate<<<N_NODES / 4, 256, 0, stream>>>(xbf, cnt + r * N_NODES,
                                                   slots + (size_t)r * N_NODES * CAP,
                                                   agg, N_NODES);
      if (r == 0)
        k_gemm<false, false><<<235 * 4, 256, 0, stream>>>(agg, SLAB, Wt + r * 512, KTOT,
                                                          8, bias, out);
      else
        k_gemm<true, false><<<235 * 4, 256, 0, stream>>>(agg, SLAB, Wt + r * 512, KTOT,
                                                         8, bias, out);
    }
    k_gemm<true, true><<<235 * 4, 256, 0, stream>>>(xbf, SLAB, Wt + 4096, KTOT,
                                                    8, bias, out);
  }
}

// Round 2
// 688.767 us; speedup vs baseline: 1.3987x; 1.3987x over previous
//
#include <hip/hip_runtime.h>
#include <hip/hip_bf16.h>

#define N_NODES 30000
#define N_REL   8
#define N_EDGES 131072
#define FEAT    512
#define KTOT    4608   // 8*512 + 512
#define CAP     32

typedef __attribute__((ext_vector_type(8))) __bf16 v8bf;
typedef __attribute__((ext_vector_type(4))) __bf16 v4bf;
typedef __attribute__((ext_vector_type(4))) float  v4f;

// ---------- async global->LDS (16B per lane, wave-uniform LDS base) ----------
static __device__ __forceinline__ void load_lds16(const void* g, void* l) {
  __builtin_amdgcn_global_load_lds(
      (const __attribute__((address_space(1))) void*)g,
      (__attribute__((address_space(3))) void*)l, 16, 0, 0);
}

// ---------- fp32 -> bf16 convert of x ----------
__global__ void k_convert_x(const float* __restrict__ x, __bf16* __restrict__ xbf) {
  int i = blockIdx.x * 256 + threadIdx.x;           // each handles 4 elems
  float4 v = ((const float4*)x)[i];
  v4bf o;
  o[0] = (__bf16)v.x; o[1] = (__bf16)v.y; o[2] = (__bf16)v.z; o[3] = (__bf16)v.w;
  ((v4bf*)xbf)[i] = o;
}

// ---------- build W_t[n][k] = W_cat[k][n] (bf16), k = r*512+i or 4096+i ----------
__global__ void k_transpose_w(const float* __restrict__ w, const float* __restrict__ lw,
                              __bf16* __restrict__ Wt) {
  __shared__ float t[32][33];
  int k0 = blockIdx.x * 32;      // 144 blocks
  int n0 = blockIdx.y * 32;      // 16 blocks
  int tx = threadIdx.x & 31, ty = threadIdx.x >> 5;   // 32 x 8
  #pragma unroll
  for (int q = 0; q < 4; ++q) {
    int k = k0 + ty + q * 8, n = n0 + tx;
    float v = (k < 4096) ? w[(size_t)k * 512 + n] : lw[(size_t)(k - 4096) * 512 + n];
    t[ty + q * 8][tx] = v;
  }
  __syncthreads();
  #pragma unroll
  for (int q = 0; q < 4; ++q) {
    int n = n0 + ty + q * 8, k = k0 + tx;
    Wt[(size_t)n * KTOT + k] = (__bf16)t[tx][ty + q * 8];
  }
}

// ---------- bucket build: per-edge atomic slot insert (u16 slots: 1 line/bucket) ----------
__global__ void k_count(const int* __restrict__ src, const int* __restrict__ dst,
                        int* __restrict__ cnt, unsigned short* __restrict__ slots) {
  int e = blockIdx.x * 256 + threadIdx.x;           // 0 .. 8*131072-1
  int rel = e >> 17;
  int d = dst[e], s = src[e];
  int bucket = rel * N_NODES + d;
  int pos = atomicAdd(&cnt[bucket], 1);
  if (pos < CAP) slots[(size_t)bucket * CAP + pos] = (unsigned short)s;
}

// ---------- aggregation: one wave per (rel,node); gather bf16 rows, fp32 acc ----------
__global__ void k_aggregate(const __bf16* __restrict__ xbf, const int* __restrict__ cnt,
                            const unsigned short* __restrict__ slots,
                            __bf16* __restrict__ out, int nBuckets) {
  int w = (blockIdx.x * blockDim.x + threadIdx.x) >> 6;
  int lane = threadIdx.x & 63;
  if (w >= nBuckets) return;
  int c = cnt[w];
  int cc = c < CAP ? c : CAP;
  const unsigned short* sl = slots + (size_t)w * CAP;
  float acc[8] = {0.f,0.f,0.f,0.f,0.f,0.f,0.f,0.f};
  for (int j = 0; j < cc; ++j) {
    int s = sl[j];
    v8bf v = *(const v8bf*)(xbf + (size_t)s * FEAT + lane * 8);
    #pragma unroll
    for (int t = 0; t < 8; ++t) acc[t] += (float)v[t];
  }
  float scale = 1.0f / (float)(c > 1 ? c : 1);
  v8bf o;
  #pragma unroll
  for (int t = 0; t < 8; ++t) o[t] = (__bf16)(acc[t] * scale);
  *(v8bf*)(out + (size_t)w * FEAT + lane * 8) = o;
}

// ---------- GEMM: C[M,512](+)= A[M,K] @ Wt[n][k]^T, 128x128 tile, mfma 16x16x32 bf16 ----------
template <bool ACCUM, bool FINAL>
__global__ __launch_bounds__(256, 2)
void k_gemm(const __bf16* __restrict__ A, size_t slabStride,
            const __bf16* __restrict__ Wt, int wtStride, int kTiles,
            const float* __restrict__ bias, float* __restrict__ C) {
  __shared__ __bf16 As[128 * 64];
  __shared__ __bf16 Bs[128 * 64];

  const int tid  = threadIdx.x;
  const int wave = tid >> 6;
  const int lane = tid & 63;
  const int lr = lane >> 3, lc = lane & 7;     // staging: row-in-chunk, 16B unit
  const int quad = lane >> 4, l15 = lane & 15; // mfma lane decomposition
  const int wRow = wave >> 1, wCol = wave & 1;

  const int mtile = blockIdx.x >> 2;
  const int ntile = blockIdx.x & 3;
  const int mBase = mtile * 128;
  const int nBase = ntile * 128;

  v4f acc[4][4];
  #pragma unroll
  for (int i = 0; i < 4; ++i)
    #pragma unroll
    for (int j = 0; j < 4; ++j) acc[i][j] = (v4f){0.f, 0.f, 0.f, 0.f};

  for (int kt = 0; kt < kTiles; ++kt) {
    const int kk = kt * 64;
    const __bf16* aT = A + (size_t)(kk >> 9) * slabStride + (kk & 511);
    #pragma unroll
    for (int t = 0; t < 4; ++t) {
      int chunk = wave * 4 + t;                 // 8 rows x 64 cols per chunk
      int row = mBase + chunk * 8 + lr;
      if (row > N_NODES - 1) row = N_NODES - 1; // clamp; masked at store
      load_lds16(aT + (size_t)row * FEAT + lc * 8, As + chunk * 512);
      int n = nBase + chunk * 8 + lr;
      load_lds16(Wt + (size_t)n * wtStride + kk + lc * 8, Bs + chunk * 512);
    }
    __syncthreads();
    #pragma unroll
    for (int ks = 0; ks < 2; ++ks) {
      v8bf af[4], bfr[4];
      #pragma unroll
      for (int mi = 0; mi < 4; ++mi) {
        int m = wRow * 64 + mi * 16 + l15;
        af[mi] = *(const v8bf*)(As + m * 64 + ks * 32 + quad * 8);
      }
      #pragma unroll
      for (int ni = 0; ni < 4; ++ni) {
        int n = wCol * 64 + ni * 16 + l15;
        bfr[ni] = *(const v8bf*)(Bs + n * 64 + ks * 32 + quad * 8);
      }
      #pragma unroll
      for (int mi = 0; mi < 4; ++mi)
        #pragma unroll
        for (int ni = 0; ni < 4; ++ni)
          acc[mi][ni] = __builtin_amdgcn_mfma_f32_16x16x32_bf16(af[mi], bfr[ni], acc[mi][ni], 0, 0, 0);
    }
    __syncthreads();
  }

  // epilogue: D row = quad*4+r, col = l15 within each 16x16 tile
  #pragma unroll
  for (int ni = 0; ni < 4; ++ni) {
    int col = nBase + wCol * 64 + ni * 16 + l15;
    float bv = FINAL ? bias[col] : 0.0f;
    #pragma unroll
    for (int mi = 0; mi < 4; ++mi) {
      int row0 = mBase + wRow * 64 + mi * 16 + quad * 4;
      #pragma unroll
      for (int r = 0; r < 4; ++r) {
        int row = row0 + r;
        if (row < N_NODES) {
          size_t idx = (size_t)row * FEAT + col;
          float v = acc[mi][ni][r];
          if (ACCUM) v += C[idx];
          if (FINAL) { v += bv; v = fmaxf(v, 0.0f); }
          C[idx] = v;
        }
      }
    }
  }
}

extern "C" void kernel_launch(void* const* d_in, const int* in_sizes, int n_in,
                              void* d_out, int out_size, void* d_ws, size_t ws_size,
                              hipStream_t stream) {
  const float* x    = (const float*)d_in[0];
  const float* w    = (const float*)d_in[1];
  const float* lw   = (const float*)d_in[2];
  const float* bias = (const float*)d_in[3];
  const int*   src  = (const int*)d_in[4];
  const int*   dst  = (const int*)d_in[5];
  float* out = (float*)d_out;

  char* ws = (char*)d_ws;
  const size_t SLAB  = (size_t)N_NODES * FEAT;              // elems per slab
  const size_t slabB = SLAB * 2;                            // 30.72 MB
  const size_t wtB   = (size_t)FEAT * KTOT * 2;             // 4.72 MB
  const size_t cntB  = (size_t)N_REL * N_NODES * 4;         // 0.96 MB
  const size_t slotB = (size_t)N_REL * N_NODES * CAP * 2;   // 15.36 MB (u16)
  const size_t fixedB = wtB + cntB + slotB;                 // 21.04 MB

  __bf16*         Wt     = (__bf16*)ws;
  int*            cnt    = (int*)(ws + wtB);
  unsigned short* slots  = (unsigned short*)(ws + wtB + cntB);
  __bf16*         slabs  = (__bf16*)(ws + fixedB);          // 16B-aligned (fixedB%16==0)

  int nSlab = (int)((ws_size - fixedB) / slabB);            // total slots incl. x slot
  if (nSlab > 9) nSlab = 9;
  int g = nSlab - 1;                                        // agg slabs per GEMM pass
  if (g > 8) g = 8;
  if (g < 1) g = 1;                                         // (ws >= ~82 MB guaranteed)
  __bf16* xbf = slabs + (size_t)g * SLAB;                   // last slot = x (bf16)

  const int nConvBlocks  = (N_NODES * FEAT / 4) / 256;      // 15000
  const int nCountBlocks = (N_REL * N_EDGES) / 256;         // 4096

  hipMemsetAsync(cnt, 0, cntB, stream);
  k_convert_x<<<nConvBlocks, 256, 0, stream>>>(x, xbf);
  k_transpose_w<<<dim3(KTOT / 32, FEAT / 32), 256, 0, stream>>>(w, lw, Wt);
  k_count<<<nCountBlocks, 256, 0, stream>>>(src, dst, cnt, slots);

  const int gemmGrid = ((N_NODES + 127) / 128) * 4;         // 235 m-tiles x 4 n-tiles

  if (g == 8) {
    // single fused GEMM: agg slabs 0..7, x at slot 8 (contiguous) -> K = 4608
    k_aggregate<<<(N_REL * N_NODES) / 4, 256, 0, stream>>>(xbf, cnt, slots, slabs,
                                                           N_REL * N_NODES);
    k_gemm<false, true><<<gemmGrid, 256, 0, stream>>>(slabs, SLAB, Wt, KTOT,
                                                      KTOT / 64, bias, out);
  } else {
    for (int r0 = 0; r0 < N_REL; r0 += g) {
      int gc = (N_REL - r0) < g ? (N_REL - r0) : g;
      k_aggregate<<<(gc * N_NODES) / 4, 256, 0, stream>>>(
          xbf, cnt + r0 * N_NODES, slots + (size_t)r0 * N_NODES * CAP,
          slabs, gc * N_NODES);
      if (r0 == 0)
        k_gemm<false, false><<<gemmGrid, 256, 0, stream>>>(
            slabs, SLAB, Wt + r0 * 512, KTOT, gc * 8, bias, out);
      else
        k_gemm<true, false><<<gemmGrid, 256, 0, stream>>>(
            slabs, SLAB, Wt + r0 * 512, KTOT, gc * 8, bias, out);
    }
    k_gemm<true, true><<<gemmGrid, 256, 0, stream>>>(xbf, SLAB, Wt + 4096, KTOT,
                                                     8, bias, out);
  }
}

// Round 3
// 611.354 us; speedup vs baseline: 1.5758x; 1.1266x over previous
//
#include <hip/hip_runtime.h>
#include <hip/hip_bf16.h>

#define N_NODES 30000
#define N_REL   8
#define N_EDGES 131072
#define FEAT    512
#define KTOT    4608   // 8*512 + 512
#define CAP     32

typedef __attribute__((ext_vector_type(8))) __bf16 v8bf;
typedef __attribute__((ext_vector_type(4))) __bf16 v4bf;
typedef __attribute__((ext_vector_type(4))) float  v4f;

// ---------- async global->LDS (16B per lane, wave-uniform LDS base) ----------
static __device__ __forceinline__ void load_lds16(const void* g, void* l) {
  __builtin_amdgcn_global_load_lds(
      (const __attribute__((address_space(1))) void*)g,
      (__attribute__((address_space(3))) void*)l, 16, 0, 0);
}

// ---------- fp32 -> bf16 convert of x ----------
__global__ void k_convert_x(const float* __restrict__ x, __bf16* __restrict__ xbf) {
  int i = blockIdx.x * 256 + threadIdx.x;           // each handles 4 elems
  float4 v = ((const float4*)x)[i];
  v4bf o;
  o[0] = (__bf16)v.x; o[1] = (__bf16)v.y; o[2] = (__bf16)v.z; o[3] = (__bf16)v.w;
  ((v4bf*)xbf)[i] = o;
}

// ---------- build W_t[n][k] = W_cat[k][n] (bf16), k = r*512+i or 4096+i ----------
__global__ void k_transpose_w(const float* __restrict__ w, const float* __restrict__ lw,
                              __bf16* __restrict__ Wt) {
  __shared__ float t[32][33];
  int k0 = blockIdx.x * 32;      // 144 blocks
  int n0 = blockIdx.y * 32;      // 16 blocks
  int tx = threadIdx.x & 31, ty = threadIdx.x >> 5;   // 32 x 8
  #pragma unroll
  for (int q = 0; q < 4; ++q) {
    int k = k0 + ty + q * 8, n = n0 + tx;
    float v = (k < 4096) ? w[(size_t)k * 512 + n] : lw[(size_t)(k - 4096) * 512 + n];
    t[ty + q * 8][tx] = v;
  }
  __syncthreads();
  #pragma unroll
  for (int q = 0; q < 4; ++q) {
    int n = n0 + ty + q * 8, k = k0 + tx;
    Wt[(size_t)n * KTOT + k] = (__bf16)t[tx][ty + q * 8];
  }
}

// ---------- bucket build: per-edge atomic slot insert (u16 slots: 1 line/bucket) ----------
__global__ void k_count(const int* __restrict__ src, const int* __restrict__ dst,
                        int* __restrict__ cnt, unsigned short* __restrict__ slots) {
  int e = blockIdx.x * 256 + threadIdx.x;           // 0 .. 8*131072-1
  int rel = e >> 17;
  int d = dst[e], s = src[e];
  int bucket = rel * N_NODES + d;
  int pos = atomicAdd(&cnt[bucket], 1);
  if (pos < CAP) slots[(size_t)bucket * CAP + pos] = (unsigned short)s;
}

// ---------- aggregation: one wave per (rel,node); 4-deep gather pipeline ----------
__global__ __launch_bounds__(256)
void k_aggregate(const __bf16* __restrict__ xbf, const int* __restrict__ cnt,
                 const unsigned short* __restrict__ slots,
                 __bf16* __restrict__ out, int nBuckets) {
  int w = (blockIdx.x * blockDim.x + threadIdx.x) >> 6;
  int lane = threadIdx.x & 63;
  if (w >= nBuckets) return;
  int c = cnt[w];
  int cc = c < CAP ? c : CAP;
  const unsigned short* sl = slots + (size_t)w * CAP;
  float acc[8] = {0.f,0.f,0.f,0.f,0.f,0.f,0.f,0.f};
  int j = 0;
  for (; j + 4 <= cc; j += 4) {
    unsigned long long p = *(const unsigned long long*)(sl + j);  // 4 u16 indices
    int s0 = (int)(p & 0xffffu), s1 = (int)((p >> 16) & 0xffffu);
    int s2 = (int)((p >> 32) & 0xffffu), s3 = (int)(p >> 48);
    v8bf v0 = *(const v8bf*)(xbf + (size_t)s0 * FEAT + lane * 8);
    v8bf v1 = *(const v8bf*)(xbf + (size_t)s1 * FEAT + lane * 8);
    v8bf v2 = *(const v8bf*)(xbf + (size_t)s2 * FEAT + lane * 8);
    v8bf v3 = *(const v8bf*)(xbf + (size_t)s3 * FEAT + lane * 8);
    #pragma unroll
    for (int t = 0; t < 8; ++t)
      acc[t] += ((float)v0[t] + (float)v1[t]) + ((float)v2[t] + (float)v3[t]);
  }
  for (; j < cc; ++j) {
    int s = sl[j];
    v8bf v = *(const v8bf*)(xbf + (size_t)s * FEAT + lane * 8);
    #pragma unroll
    for (int t = 0; t < 8; ++t) acc[t] += (float)v[t];
  }
  float scale = 1.0f / (float)(c > 1 ? c : 1);
  v8bf o;
  #pragma unroll
  for (int t = 0; t < 8; ++t) o[t] = (__bf16)(acc[t] * scale);
  *(v8bf*)(out + (size_t)w * FEAT + lane * 8) = o;
}

// ---------- GEMM: C[M,512](+)= A[M,K] @ Wt[n][k]^T, 128x128 tile, mfma 16x16x32 bf16 ----
// LDS XOR-swizzle: LDS slot (row r, chunk sc) holds global 16B-chunk sc^r of that row,
// arranged at staging time by permuting each lane's GLOBAL address (LDS dest of
// global_load_lds is fixed at base+lane*16). Fragment reads hit all 32 banks 2-way.
template <bool ACCUM, bool FINAL>
__global__ __launch_bounds__(256, 4)
void k_gemm(const __bf16* __restrict__ A, size_t slabStride,
            const __bf16* __restrict__ Wt, int wtStride, int kTiles,
            const float* __restrict__ bias, float* __restrict__ C) {
  __shared__ __bf16 As[128 * 64];
  __shared__ __bf16 Bs[128 * 64];

  const int tid  = threadIdx.x;
  const int wave = tid >> 6;
  const int lane = tid & 63;
  const int lr = lane >> 3, lc = lane & 7;     // staging: row-in-chunk, 16B slot
  const int gc = (lc ^ lr) * 8;                // swizzled global chunk (elem offset)
  const int quad = lane >> 4, l15 = lane & 15; // mfma lane decomposition
  const int wRow = wave >> 1, wCol = wave & 1;

  const int mtile = blockIdx.x >> 2;
  const int ntile = blockIdx.x & 3;
  const int mBase = mtile * 128;
  const int nBase = ntile * 128;

  v4f acc[4][4];
  #pragma unroll
  for (int i = 0; i < 4; ++i)
    #pragma unroll
    for (int j = 0; j < 4; ++j) acc[i][j] = (v4f){0.f, 0.f, 0.f, 0.f};

  for (int kt = 0; kt < kTiles; ++kt) {
    const int kk = kt * 64;
    const __bf16* aT = A + (size_t)(kk >> 9) * slabStride + (kk & 511);
    #pragma unroll
    for (int t = 0; t < 4; ++t) {
      int chunk = wave * 4 + t;                 // 8 rows x 64 cols per chunk
      int row = mBase + chunk * 8 + lr;
      if (row > N_NODES - 1) row = N_NODES - 1; // clamp; masked at store
      load_lds16(aT + (size_t)row * FEAT + gc, As + chunk * 512);
      int n = nBase + chunk * 8 + lr;
      load_lds16(Wt + (size_t)n * wtStride + kk + gc, Bs + chunk * 512);
    }
    __syncthreads();
    #pragma unroll
    for (int ks = 0; ks < 2; ++ks) {
      const int q = ks * 4 + quad;              // 16B chunk wanted this phase
      v8bf af[4], bfr[4];
      #pragma unroll
      for (int mi = 0; mi < 4; ++mi) {
        int m = wRow * 64 + mi * 16 + l15;
        af[mi] = *(const v8bf*)(As + m * 64 + ((q ^ (m & 7)) * 8));
      }
      #pragma unroll
      for (int ni = 0; ni < 4; ++ni) {
        int n = wCol * 64 + ni * 16 + l15;
        bfr[ni] = *(const v8bf*)(Bs + n * 64 + ((q ^ (n & 7)) * 8));
      }
      #pragma unroll
      for (int mi = 0; mi < 4; ++mi)
        #pragma unroll
        for (int ni = 0; ni < 4; ++ni)
          acc[mi][ni] = __builtin_amdgcn_mfma_f32_16x16x32_bf16(af[mi], bfr[ni], acc[mi][ni], 0, 0, 0);
    }
    __syncthreads();
  }

  // epilogue: D row = quad*4+r, col = l15 within each 16x16 tile
  #pragma unroll
  for (int ni = 0; ni < 4; ++ni) {
    int col = nBase + wCol * 64 + ni * 16 + l15;
    float bv = FINAL ? bias[col] : 0.0f;
    #pragma unroll
    for (int mi = 0; mi < 4; ++mi) {
      int row0 = mBase + wRow * 64 + mi * 16 + quad * 4;
      #pragma unroll
      for (int r = 0; r < 4; ++r) {
        int row = row0 + r;
        if (row < N_NODES) {
          size_t idx = (size_t)row * FEAT + col;
          float v = acc[mi][ni][r];
          if (ACCUM) v += C[idx];
          if (FINAL) { v += bv; v = fmaxf(v, 0.0f); }
          C[idx] = v;
        }
      }
    }
  }
}

extern "C" void kernel_launch(void* const* d_in, const int* in_sizes, int n_in,
                              void* d_out, int out_size, void* d_ws, size_t ws_size,
                              hipStream_t stream) {
  const float* x    = (const float*)d_in[0];
  const float* w    = (const float*)d_in[1];
  const float* lw   = (const float*)d_in[2];
  const float* bias = (const float*)d_in[3];
  const int*   src  = (const int*)d_in[4];
  const int*   dst  = (const int*)d_in[5];
  float* out = (float*)d_out;

  char* ws = (char*)d_ws;
  const size_t SLAB  = (size_t)N_NODES * FEAT;              // elems per slab
  const size_t slabB = SLAB * 2;                            // 30.72 MB
  const size_t wtB   = (size_t)FEAT * KTOT * 2;             // 4.72 MB
  const size_t cntB  = (size_t)N_REL * N_NODES * 4;         // 0.96 MB
  const size_t slotB = (size_t)N_REL * N_NODES * CAP * 2;   // 15.36 MB (u16)
  const size_t fixedB = wtB + cntB + slotB;                 // 21.04 MB

  __bf16*         Wt     = (__bf16*)ws;
  int*            cnt    = (int*)(ws + wtB);
  unsigned short* slots  = (unsigned short*)(ws + wtB + cntB);
  __bf16*         slabs  = (__bf16*)(ws + fixedB);          // 16B-aligned

  int nSlab = (int)((ws_size - fixedB) / slabB);            // total slots incl. x slot
  if (nSlab > 9) nSlab = 9;
  int g = nSlab - 1;                                        // agg slabs per GEMM pass
  if (g > 8) g = 8;
  if (g < 1) g = 1;
  __bf16* xbf = slabs + (size_t)g * SLAB;                   // last slot = x (bf16)

  const int nConvBlocks  = (N_NODES * FEAT / 4) / 256;      // 15000
  const int nCountBlocks = (N_REL * N_EDGES) / 256;         // 4096

  hipMemsetAsync(cnt, 0, cntB, stream);
  k_convert_x<<<nConvBlocks, 256, 0, stream>>>(x, xbf);
  k_transpose_w<<<dim3(KTOT / 32, FEAT / 32), 256, 0, stream>>>(w, lw, Wt);
  k_count<<<nCountBlocks, 256, 0, stream>>>(src, dst, cnt, slots);

  const int gemmGrid = ((N_NODES + 127) / 128) * 4;         // 235 m-tiles x 4 n-tiles

  if (g == 8) {
    // single fused GEMM: agg slabs 0..7, x at slot 8 (contiguous) -> K = 4608
    k_aggregate<<<(N_REL * N_NODES) / 4, 256, 0, stream>>>(xbf, cnt, slots, slabs,
                                                           N_REL * N_NODES);
    k_gemm<false, true><<<gemmGrid, 256, 0, stream>>>(slabs, SLAB, Wt, KTOT,
                                                      KTOT / 64, bias, out);
  } else {
    for (int r0 = 0; r0 < N_REL; r0 += g) {
      int gc2 = (N_REL - r0) < g ? (N_REL - r0) : g;
      k_aggregate<<<(gc2 * N_NODES) / 4, 256, 0, stream>>>(
          xbf, cnt + r0 * N_NODES, slots + (size_t)r0 * N_NODES * CAP,
          slabs, gc2 * N_NODES);
      if (r0 == 0)
        k_gemm<false, false><<<gemmGrid, 256, 0, stream>>>(
            slabs, SLAB, Wt + r0 * 512, KTOT, gc2 * 8, bias, out);
      else
        k_gemm<true, false><<<gemmGrid, 256, 0, stream>>>(
            slabs, SLAB, Wt + r0 * 512, KTOT, gc2 * 8, bias, out);
    }
    k_gemm<true, true><<<gemmGrid, 256, 0, stream>>>(xbf, SLAB, Wt + 4096, KTOT,
                                                     8, bias, out);
  }
}